// Round 3
// baseline (212.763 us; speedup 1.0000x reference)
//
#include <hip/hip_runtime.h>
#include <math.h>

// ---------------------------------------------------------------------------
// Round 7: occupancy fix. Round 6 (94.4 us) was capped at 16 waves/CU:
// LDS 40 KB/block x 4 blocks/CU = 160 KiB, but only 4 waves/block.
//  - ONE change: 512-thread blocks (8 waves, 8 tiles/block). Same 40 KB
//    frag table per block, same 4-blocks/CU LDS cap, but now 32 waves/CU
//    = 8 waves/SIMD (hardware max). VGPR=52 fits the <=64 budget;
//    __launch_bounds__(512, 8) pins it.
//  - Per-tile math BIT-IDENTICAL to round 6 (verified absmax 0.0059).
// ---------------------------------------------------------------------------

typedef short bf16x8 __attribute__((ext_vector_type(8)));
typedef float f32x4  __attribute__((ext_vector_type(4)));

#define MFMA16(A, B, C) __builtin_amdgcn_mfma_f32_16x16x32_bf16((A), (B), (C), 0, 0, 0)
#define PBOUND 0.99999f /* 1 - 1e-5 */

static __device__ __forceinline__ float artanh_c(float n) {
    float z = fminf(n, PBOUND);
    return 0.5f * __logf((1.0f + z) / (1.0f - z));
}
static __device__ __forceinline__ float tanh_pos(float n) {
    float e = __expf(-2.0f * n);
    return (1.0f - e) / (1.0f + e);
}
// sum across the 4 quads (lanes ^16, ^32); result broadcast to all 4
static __device__ __forceinline__ float red4q(float v) {
    v += __shfl_xor(v, 16);
    v += __shfl_xor(v, 32);
    return v;
}
// truncation split: hi = top 16 bits, lo = bf16(x - hi). ~4 ops.
static __device__ __forceinline__ void split_trunc(float x, short* h, short* l) {
    unsigned u = __builtin_bit_cast(unsigned, x);
    *h = (short)(u >> 16);
    float fh = __builtin_bit_cast(float, u & 0xFFFF0000u);
    float r = x - fh;
    unsigned ur = __builtin_bit_cast(unsigned, r);
    *l = (short)(ur >> 16);
}

// B-slot kk = 32*kt + 8q + jj holds natural feature kperm(kk) of the previous
// layer's D output (t = 2*kt + (jj>>2), r = jj&3, feature = 16t + 4q + r).
static __device__ __forceinline__ int kperm(int kk) {
    return 32 * (kk >> 5) + 16 * ((kk & 7) >> 2) + 4 * ((kk >> 3) & 3) + (kk & 3);
}

template <int NT>
static __device__ __forceinline__ float dotred(const f32x4* a, const f32x4* b) {
    float p = 0.0f;
#pragma unroll
    for (int t = 0; t < NT; ++t)
#pragma unroll
        for (int r = 0; r < 4; ++r) p = fmaf(a[t][r], b[t][r], p);
    return red4q(p);
}

// expmap with pending scale: true vec = lam*d. Updates lam, X2 (true |.|^2).
template <int NT>
static __device__ __forceinline__ void expmap_fold(const f32x4* d, float& lam, float& X2) {
    float p = 0.0f;
#pragma unroll
    for (int t = 0; t < NT; ++t)
#pragma unroll
        for (int r = 0; r < 4; ++r) p = fmaf(d[t][r], d[t][r], p);
    p = red4q(p);
    float nU = fmaxf(lam * sqrtf(p), 1e-15f);
    float th = tanh_pos(nU);
    lam = lam * th / nU;
    X2 = th * th;
}

static __device__ __forceinline__ void logmap_fold(float& lam, float X2) {
    float n = fmaxf(sqrtf(X2), 1e-15f);
    lam *= artanh_c(n) / n;
}

// d <- raw(mobius_add(lam*d, bias)); lam <- 1/den; X2 updated analytically
template <int NT>
static __device__ __forceinline__ void mobius_bias_fold(f32x4* d, const f32x4* bv,
                                                        float& lam, float& X2, float b2) {
    float C = dotred<NT>(d, bv);
    float xy = lam * C;
    float a = 1.0f + 2.0f * xy + b2;
    float b = 1.0f - X2;
    float den = fmaxf(fmaf(X2, b2, 1.0f + 2.0f * xy), 1e-15f);
    float inv = 1.0f / den;
    float A = a * lam;
#pragma unroll
    for (int t = 0; t < NT; ++t)
#pragma unroll
        for (int r = 0; r < 4; ++r) d[t][r] = fmaf(A, d[t][r], b * bv[t][r]);
    lam = inv;
    X2 = (a * a * X2 + 2.0f * a * b * xy + b * b * b2) * (inv * inv);
}

// split 16 D-regs into the two next-layer B-frag hi/lo pairs
static __device__ __forceinline__ void split_d16(const f32x4* d, bf16x8* bh, bf16x8* bl) {
#pragma unroll
    for (int kt = 0; kt < 2; ++kt)
#pragma unroll
        for (int jj = 0; jj < 8; ++jj) {
            short hh, ll;
            split_trunc(d[2 * kt + (jj >> 2)][jj & 3], &hh, &ll);
            bh[kt][jj] = hh;
            bl[kt][jj] = ll;
        }
}

// matvec with K=64 (2 kt blocks), NT output tiles; frags at logical id
// fbase + 2t + kt (hi = phys 2f, lo = 2f+1). F points at LDS.
template <int NT>
static __device__ __forceinline__ void layer_mm(const bf16x8* F, int fbase,
                                                int lane, const bf16x8* ah,
                                                const bf16x8* al, f32x4* d) {
#pragma unroll
    for (int t = 0; t < NT; ++t) {
        f32x4 c = {0.0f, 0.0f, 0.0f, 0.0f};
#pragma unroll
        for (int kt = 0; kt < 2; ++kt) {
            int f = fbase + 2 * t + kt;
            bf16x8 wh = F[(2 * f) * 64 + lane];
            bf16x8 wl = F[(2 * f + 1) * 64 + lane];
            c = MFMA16(wh, ah[kt], c);
            c = MFMA16(wl, ah[kt], c);
            c = MFMA16(wh, al[kt], c);
        }
        d[t] = c;
    }
}

// branch: load x-row chunk (B-frag natural k), logmap fold, split, matvec
// (A = Wc^T frags at fbase..fbase+3), expmap fold.
static __device__ __forceinline__ void branch_stage(const float* __restrict__ x, size_t row,
                                                    int q, int lane, int fbase,
                                                    const bf16x8* F, f32x4* d,
                                                    float& lam, float& X2) {
    const float4* p4 = (const float4*)(x + row * 32 + q * 8);
    float4 va = p4[0], vb = p4[1];
    float v[8] = {va.x, va.y, va.z, va.w, vb.x, vb.y, vb.z, vb.w};
    float n2 = 0.0f;
#pragma unroll
    for (int i = 0; i < 8; ++i) n2 = fmaf(v[i], v[i], n2);
    n2 = red4q(n2);
    float n = fmaxf(sqrtf(n2), 1e-15f);
    lam = artanh_c(n) / n; // logmap scale, folded past the matvec
    bf16x8 bh, bl;
#pragma unroll
    for (int i = 0; i < 8; ++i) {
        short hh, ll;
        split_trunc(v[i], &hh, &ll);
        bh[i] = hh;
        bl[i] = ll;
    }
#pragma unroll
    for (int t = 0; t < 4; ++t) {
        bf16x8 wh = F[(2 * (fbase + t)) * 64 + lane];
        bf16x8 wl = F[(2 * (fbase + t) + 1) * 64 + lane];
        f32x4 c = {0.0f, 0.0f, 0.0f, 0.0f};
        c = MFMA16(wh, bh, c);
        c = MFMA16(wl, bh, c);
        c = MFMA16(wh, bl, c);
        d[t] = c;
    }
    expmap_fold<4>(d, lam, X2);
}

// ---------------------------------------------------------------------------
// Setup: weight fragments (A-operand layout, RNE hi/lo split; W0/W1 with
// kperm'd K) + bias squared norms. Unchanged.
// ---------------------------------------------------------------------------
__global__ void build_frags(const float* __restrict__ Wc1, const float* __restrict__ Wc2,
                            const float* __restrict__ W0, const float* __restrict__ W1,
                            const float* __restrict__ bc, const float* __restrict__ b0,
                            const float* __restrict__ b1, unsigned short* __restrict__ fout,
                            float* __restrict__ norms) {
    int tid = blockIdx.x * blockDim.x + threadIdx.x;
    const int total = 40 * 512;
    if (tid < total) {
        int p = tid >> 9, within = tid & 511;
        int lane = within >> 3, jj = within & 7;
        int f = p >> 1, isLo = p & 1;
        int m = lane & 15, kq = lane >> 4;
        int kl = kq * 8 + jj; // A-frag k within the 32-block
        float w;
        if (f < 4)      w = Wc1[kl * 64 + f * 16 + m];
        else if (f < 8) w = Wc2[kl * 64 + (f - 4) * 16 + m];
        else if (f < 16) {
            int t = (f - 8) >> 1, kt = (f - 8) & 1;
            w = W0[kperm(32 * kt + kl) * 64 + t * 16 + m];
        } else {
            int t = (f - 16) >> 1, kt = (f - 16) & 1;
            w = W1[kperm(32 * kt + kl) * 32 + t * 16 + m];
        }
        unsigned u = __builtin_bit_cast(unsigned, w);
        unsigned r = u + (0x7FFFu + ((u >> 16) & 1u)); // RNE
        unsigned short hi = (unsigned short)(r >> 16);
        float fhi = __builtin_bit_cast(float, (unsigned)hi << 16);
        float res = w - fhi;
        unsigned ul = __builtin_bit_cast(unsigned, res);
        unsigned rl = ul + (0x7FFFu + ((ul >> 16) & 1u));
        fout[tid] = isLo ? (unsigned short)(rl >> 16) : hi;
    } else if (tid < total + 3) {
        int which = tid - total;
        const float* b = which == 0 ? bc : (which == 1 ? b0 : b1);
        int n = which == 2 ? 32 : 64;
        float s = 0.0f;
        for (int i = 0; i < n; ++i) s += b[i] * b[i];
        norms[which] = s;
    }
}

// ---------------------------------------------------------------------------
// Main: 8 waves/block (512 thr), one 16-row tile per wave, frag table in LDS.
// 40 KB LDS x 4 blocks/CU = 160 KiB; 32 waves/CU = 8 waves/SIMD (HW max).
// ---------------------------------------------------------------------------
__global__ void __launch_bounds__(512, 8) poincare_mfma5(
    const float* __restrict__ x1, const float* __restrict__ x2,
    const float* __restrict__ bc, const float* __restrict__ b0,
    const float* __restrict__ b1, const unsigned short* __restrict__ frags,
    const float* __restrict__ norms, float* __restrict__ out, int ntiles) {
    __shared__ __align__(16) unsigned short smem[20480]; // 40 KB frag table

    const int tid = threadIdx.x;
    {
        // stage 40960 B: 512 threads x 5 x 16 B, coalesced, once per block
        const uint4* g = (const uint4*)frags;
        uint4* s = (uint4*)smem;
#pragma unroll
        for (int i = 0; i < 5; ++i) s[tid + i * 512] = g[tid + i * 512];
    }
    __syncthreads();

    const int lane = tid & 63;
    const int wid = tid >> 6;
    const int tile = blockIdx.x * 8 + wid;
    if (tile >= ntiles) return; // after the barrier: safe
    const int j = lane & 15, q = lane >> 4;
    const size_t row = (size_t)tile * 16 + j;

    const bf16x8* F = (const bf16x8*)smem; // F[phys*64 + lane], LDS-resident
    const float bc2 = norms[0], b02 = norms[1], b12 = norms[2];

    // ---- branches
    f32x4 d1[4], d2[4];
    float lam1, X2, lam2, Y2;
    branch_stage(x1, row, q, lane, 0, F, d1, lam1, X2);
    branch_stage(x2, row, q, lane, 4, F, d2, lam2, Y2);

    // ---- mobius_add(h1, h2), scales folded
    {
        float C = dotred<4>(d1, d2);
        float xy = lam1 * lam2 * C;
        float a = 1.0f + 2.0f * xy + Y2;
        float b = 1.0f - X2;
        float den = fmaxf(fmaf(X2, Y2, 1.0f + 2.0f * xy), 1e-15f);
        float inv = 1.0f / den;
        float A = a * lam1, B = b * lam2;
#pragma unroll
        for (int t = 0; t < 4; ++t)
#pragma unroll
            for (int r = 0; r < 4; ++r) d1[t][r] = fmaf(A, d1[t][r], B * d2[t][r]);
        lam1 = inv;
        X2 = (a * a * X2 + 2.0f * a * b * xy + b * b * Y2) * (inv * inv);
    }
    // ---- + bc  (bias vectors load in natural feature order: f = 16t+4q+r)
    f32x4 bcv[4];
#pragma unroll
    for (int t = 0; t < 4; ++t) bcv[t] = *(const f32x4*)(bc + t * 16 + q * 4);
    mobius_bias_fold<4>(d1, bcv, lam1, X2, bc2);
    logmap_fold(lam1, X2);

    // ---- layer 0 (K=64, kperm'd weights; D feeds B-frags directly)
    bf16x8 ah[2], al[2];
    split_d16(d1, ah, al);
    f32x4 d0[4];
    layer_mm<4>(F, 8, lane, ah, al, d0);
    expmap_fold<4>(d0, lam1, X2);
    f32x4 b0v[4];
#pragma unroll
    for (int t = 0; t < 4; ++t) b0v[t] = *(const f32x4*)(b0 + t * 16 + q * 4);
    mobius_bias_fold<4>(d0, b0v, lam1, X2, b02);
    logmap_fold(lam1, X2);

    // ---- layer 1 (N=32)
    split_d16(d0, ah, al);
    f32x4 dO[2];
    layer_mm<2>(F, 16, lane, ah, al, dO);
    expmap_fold<2>(dO, lam1, X2);

    // ---- final mobius bias, inv folded into the store scale
    f32x4 b1v[2];
#pragma unroll
    for (int t = 0; t < 2; ++t) b1v[t] = *(const f32x4*)(b1 + t * 16 + q * 4);
    {
        float C = dotred<2>(dO, b1v);
        float xy = lam1 * C;
        float a = 1.0f + 2.0f * xy + b12;
        float b = 1.0f - X2;
        float den = fmaxf(fmaf(X2, b12, 1.0f + 2.0f * xy), 1e-15f);
        float inv = 1.0f / den;
        float F1 = inv * a * lam1, F2 = inv * b;
#pragma unroll
        for (int t = 0; t < 2; ++t) {
            f32x4 res;
#pragma unroll
            for (int r = 0; r < 4; ++r) res[r] = fmaf(F1, dO[t][r], F2 * b1v[t][r]);
            *(f32x4*)(out + row * 32 + t * 16 + q * 4) = res;
        }
    }
}

extern "C" void kernel_launch(void* const* d_in, const int* in_sizes, int n_in,
                              void* d_out, int out_size, void* d_ws, size_t ws_size,
                              hipStream_t stream) {
    const float* x1  = (const float*)d_in[0];
    const float* x2  = (const float*)d_in[1];
    const float* Wc1 = (const float*)d_in[2];
    const float* Wc2 = (const float*)d_in[3];
    const float* bc  = (const float*)d_in[4];
    const float* W0  = (const float*)d_in[5];
    const float* b0  = (const float*)d_in[6];
    const float* W1  = (const float*)d_in[7];
    const float* b1  = (const float*)d_in[8];
    float* out = (float*)d_out;

    unsigned short* frags = (unsigned short*)d_ws;            // 40 KB
    float* norms = (float*)((char*)d_ws + 40 * 512 * 2);      // 3 floats

    const int nrows  = in_sizes[0] / 32;
    const int ntiles = nrows / 16;
    const int nblocks = (ntiles + 7) / 8;

    build_frags<<<81, 256, 0, stream>>>(Wc1, Wc2, W0, W1, bc, b0, b1, frags, norms);
    poincare_mfma5<<<nblocks, 512, 0, stream>>>(x1, x2, bc, b0, b1, frags, norms, out, ntiles);
}

// Round 4
// 199.513 us; speedup vs baseline: 1.0664x; 1.0664x over previous
//
#include <hip/hip_runtime.h>
#include <math.h>

// ---------------------------------------------------------------------------
// Round 8: 32x32x16 MFMA restructure — halve per-row work.
//  - One wave = 32-row tile (was 16). Scalar fold chains + shuffles amortize
//    over 2x rows; MFMA count and frag reads halve per row.
//  - Each row lives on 2 lanes (r, r+32): every reduction = 1 shfl_xor(32).
//  - D layout (verified m74/m101): col=lane&31, row=(reg&3)+8*(reg>>2)+4*h.
//    Layer-to-layer: B-frag block kt <- regs 8*(kt&1)..+7 of d[kt>>1], i.e.
//    plain register order; feature permutation folded into weights (kperm32).
//  - Scalar fold code byte-identical to verified round 6/7 kernels.
//  - 256-thr blocks, launch_bounds(256,4): VGPR<=128, 4 blocks x 40KB LDS.
// ---------------------------------------------------------------------------

typedef short bf16x8 __attribute__((ext_vector_type(8)));
typedef float f32x4  __attribute__((ext_vector_type(4)));
typedef float f32x16 __attribute__((ext_vector_type(16)));

#define MFMA32(A, B, C) __builtin_amdgcn_mfma_f32_32x32x16_bf16((A), (B), (C), 0, 0, 0)
#define PBOUND 0.99999f /* 1 - 1e-5 */

static __device__ __forceinline__ float artanh_c(float n) {
    float z = fminf(n, PBOUND);
    return 0.5f * __logf((1.0f + z) / (1.0f - z));
}
static __device__ __forceinline__ float tanh_pos(float n) {
    float e = __expf(-2.0f * n);
    return (1.0f - e) / (1.0f + e);
}
// row r is held by lanes r and r+32: single-swap reduction, broadcast to both
static __device__ __forceinline__ float red2h(float v) {
    return v + __shfl_xor(v, 32);
}
// truncation split: hi = top 16 bits, lo = bf16(x - hi). ~4 ops.
static __device__ __forceinline__ void split_trunc(float x, short* h, short* l) {
    unsigned u = __builtin_bit_cast(unsigned, x);
    *h = (short)(u >> 16);
    float fh = __builtin_bit_cast(float, u & 0xFFFF0000u);
    float r = x - fh;
    unsigned ur = __builtin_bit_cast(unsigned, r);
    *l = (short)(ur >> 16);
}

// K-slot s (0..63) of a 64-dim layer holds natural feature kperm32(s) of the
// previous layer's D output. Derivation: slot s = kt*16 + h*8 + j must map to
// a feature held by lane-half h: f = (kt>>1)*32 + 8*((j>>2)+2*(kt&1)) + 4h +
// (j&3). Then B-frag block kt = regs 8*(kt&1)..+7 of d[kt>>1], in order.
static __device__ __forceinline__ int kperm32(int s) {
    return (s >> 5) * 32 + (((s >> 2) & 1) + 2 * ((s >> 4) & 1)) * 8 +
           ((s >> 3) & 1) * 4 + (s & 3);
}

static __device__ __forceinline__ f32x16 zero16() {
    f32x16 z;
#pragma unroll
    for (int r = 0; r < 16; ++r) z[r] = 0.0f;
    return z;
}

template <int NV>
static __device__ __forceinline__ float dotred32(const f32x16* a, const f32x16* b) {
    float p = 0.0f;
#pragma unroll
    for (int v = 0; v < NV; ++v)
#pragma unroll
        for (int r = 0; r < 16; ++r) p = fmaf(a[v][r], b[v][r], p);
    return red2h(p);
}

// expmap with pending scale: true vec = lam*d. Updates lam, X2 (true |.|^2).
template <int NV>
static __device__ __forceinline__ void expmap_fold32(const f32x16* d, float& lam, float& X2) {
    float p = 0.0f;
#pragma unroll
    for (int v = 0; v < NV; ++v)
#pragma unroll
        for (int r = 0; r < 16; ++r) p = fmaf(d[v][r], d[v][r], p);
    p = red2h(p);
    float nU = fmaxf(lam * sqrtf(p), 1e-15f);
    float th = tanh_pos(nU);
    lam = lam * th / nU;
    X2 = th * th;
}

static __device__ __forceinline__ void logmap_fold(float& lam, float X2) {
    float n = fmaxf(sqrtf(X2), 1e-15f);
    lam *= artanh_c(n) / n;
}

// d <- raw(mobius_add(lam*d, bias)); lam <- 1/den; X2 updated analytically
template <int NV>
static __device__ __forceinline__ void mobius_bias_fold32(f32x16* d, const f32x16* bv,
                                                          float& lam, float& X2, float b2) {
    float C = dotred32<NV>(d, bv);
    float xy = lam * C;
    float a = 1.0f + 2.0f * xy + b2;
    float b = 1.0f - X2;
    float den = fmaxf(fmaf(X2, b2, 1.0f + 2.0f * xy), 1e-15f);
    float inv = 1.0f / den;
    float A = a * lam;
#pragma unroll
    for (int v = 0; v < NV; ++v)
#pragma unroll
        for (int r = 0; r < 16; ++r) d[v][r] = fmaf(A, d[v][r], b * bv[v][r]);
    lam = inv;
    X2 = (a * a * X2 + 2.0f * a * b * xy + b * b * b2) * (inv * inv);
}

// split the 32 D-regs (2 x f32x16) into the 4 next-layer B-frag hi/lo pairs.
// Block kt <- regs 8*(kt&1)..+7 of d[kt>>1] (plain order; perm is in weights).
static __device__ __forceinline__ void split_d32(const f32x16 d[2], bf16x8 bh[4], bf16x8 bl[4]) {
#pragma unroll
    for (int kt = 0; kt < 4; ++kt)
#pragma unroll
        for (int j = 0; j < 8; ++j) {
            short hh, ll;
            split_trunc(d[kt >> 1][8 * (kt & 1) + j], &hh, &ll);
            bh[kt][j] = hh;
            bl[kt][j] = ll;
        }
}

// bias vector in D-register order: reg-group g holds features off+8g+4h+(0..3)
static __device__ __forceinline__ f32x16 loadb(const float* __restrict__ b, int off, int h) {
    f32x16 r;
#pragma unroll
    for (int g = 0; g < 4; ++g) {
        f32x4 v = *(const f32x4*)(b + off + g * 8 + h * 4);
#pragma unroll
        for (int k = 0; k < 4; ++k) r[g * 4 + k] = v[k];
    }
    return r;
}

// K=64 matvec: NT output 32-tiles, 4 kt blocks; frag f = fbase + t*4 + kt
template <int NT>
static __device__ __forceinline__ void layer_mm32(const bf16x8* F, int fbase, int lane,
                                                  const bf16x8 ah[4], const bf16x8 al[4],
                                                  f32x16* d) {
#pragma unroll
    for (int t = 0; t < NT; ++t) {
        f32x16 c = zero16();
#pragma unroll
        for (int kt = 0; kt < 4; ++kt) {
            int f = fbase + t * 4 + kt;
            bf16x8 wh = F[(2 * f) * 64 + lane];
            bf16x8 wl = F[(2 * f + 1) * 64 + lane];
            c = MFMA32(wh, ah[kt], c);
            c = MFMA32(wl, ah[kt], c);
            c = MFMA32(wh, al[kt], c);
        }
        d[t] = c;
    }
}

// branch: lane (r,h) loads row cols [h*8..h*8+7] and [16+h*8..+7] (natural
// B k-order), logmap fold, split, matvec (A frags fbase + t*2 + kt), expmap.
static __device__ __forceinline__ void branch_stage32(const float* __restrict__ x, size_t row,
                                                      int h, int lane, int fbase,
                                                      const bf16x8* F, f32x16* d,
                                                      float& lam, float& X2) {
    const float* base = x + row * 32 + h * 8;
    f32x4 va = *(const f32x4*)(base);
    f32x4 vb = *(const f32x4*)(base + 4);
    f32x4 vc = *(const f32x4*)(base + 16);
    f32x4 vd = *(const f32x4*)(base + 20);
    float v[16] = {va[0], va[1], va[2], va[3], vb[0], vb[1], vb[2], vb[3],
                   vc[0], vc[1], vc[2], vc[3], vd[0], vd[1], vd[2], vd[3]};
    float n2 = 0.0f;
#pragma unroll
    for (int i = 0; i < 16; ++i) n2 = fmaf(v[i], v[i], n2);
    n2 = red2h(n2);
    float n = fmaxf(sqrtf(n2), 1e-15f);
    lam = artanh_c(n) / n; // logmap scale, folded past the matvec
    bf16x8 bh[2], bl[2];
#pragma unroll
    for (int kt = 0; kt < 2; ++kt)
#pragma unroll
        for (int j = 0; j < 8; ++j) {
            short hh, ll;
            split_trunc(v[kt * 8 + j], &hh, &ll);
            bh[kt][j] = hh;
            bl[kt][j] = ll;
        }
#pragma unroll
    for (int t = 0; t < 2; ++t) {
        f32x16 c = zero16();
#pragma unroll
        for (int kt = 0; kt < 2; ++kt) {
            int f = fbase + t * 2 + kt;
            bf16x8 wh = F[(2 * f) * 64 + lane];
            bf16x8 wl = F[(2 * f + 1) * 64 + lane];
            c = MFMA32(wh, bh[kt], c);
            c = MFMA32(wl, bh[kt], c);
            c = MFMA32(wh, bl[kt], c);
        }
        d[t] = c;
    }
    expmap_fold32<2>(d, lam, X2);
}

// ---------------------------------------------------------------------------
// Setup: A-operand frags for 32x32x16 (row m = lane&31, k = (lane>>5)*8 + j),
// RNE hi/lo split; W0/W1 K pre-permuted by kperm32. Bias squared norms.
//  logical f: 0-3 Wc1(t*2+kt), 4-7 Wc2, 8-15 W0(t*4+kt), 16-19 W1(kt).
//  phys p = 2f + isLo. 40 phys x 1024 B = 40 KB.
// ---------------------------------------------------------------------------
__global__ void build_frags(const float* __restrict__ Wc1, const float* __restrict__ Wc2,
                            const float* __restrict__ W0, const float* __restrict__ W1,
                            const float* __restrict__ bc, const float* __restrict__ b0,
                            const float* __restrict__ b1, unsigned short* __restrict__ fout,
                            float* __restrict__ norms) {
    int tid = blockIdx.x * blockDim.x + threadIdx.x;
    const int total = 40 * 512;
    if (tid < total) {
        int p = tid >> 9, within = tid & 511;
        int lane = within >> 3, jj = within & 7;
        int f = p >> 1, isLo = p & 1;
        int m = lane & 31, ha = lane >> 5;
        int kin = ha * 8 + jj; // k within the 16-block
        float w;
        if (f < 4) {
            int t = f >> 1, kt = f & 1;
            w = Wc1[(kt * 16 + kin) * 64 + t * 32 + m];
        } else if (f < 8) {
            int g = f - 4, t = g >> 1, kt = g & 1;
            w = Wc2[(kt * 16 + kin) * 64 + t * 32 + m];
        } else if (f < 16) {
            int g = f - 8, t = g >> 2, kt = g & 3;
            w = W0[kperm32(kt * 16 + kin) * 64 + t * 32 + m];
        } else {
            int kt = f - 16;
            w = W1[kperm32(kt * 16 + kin) * 32 + m];
        }
        unsigned u = __builtin_bit_cast(unsigned, w);
        unsigned r = u + (0x7FFFu + ((u >> 16) & 1u)); // RNE
        unsigned short hi = (unsigned short)(r >> 16);
        float fhi = __builtin_bit_cast(float, (unsigned)hi << 16);
        float res = w - fhi;
        unsigned ul = __builtin_bit_cast(unsigned, res);
        unsigned rl = ul + (0x7FFFu + ((ul >> 16) & 1u));
        fout[tid] = isLo ? (unsigned short)(rl >> 16) : hi;
    } else if (tid < total + 3) {
        int which = tid - total;
        const float* b = which == 0 ? bc : (which == 1 ? b0 : b1);
        int n = which == 2 ? 32 : 64;
        float s = 0.0f;
        for (int i = 0; i < n; ++i) s += b[i] * b[i];
        norms[which] = s;
    }
}

// ---------------------------------------------------------------------------
// Main: 4 waves/block (256 thr), one 32-row tile per wave, frag table in LDS.
// 40 KB x 4 blocks/CU = 160 KiB; VGPR<=128 -> 16 waves/CU.
// ---------------------------------------------------------------------------
__global__ void __launch_bounds__(256, 4) poincare_mfma6(
    const float* __restrict__ x1, const float* __restrict__ x2,
    const float* __restrict__ bc, const float* __restrict__ b0,
    const float* __restrict__ b1, const unsigned short* __restrict__ frags,
    const float* __restrict__ norms, float* __restrict__ out, int ntiles) {
    __shared__ __align__(16) unsigned short smem[20480]; // 40 KB frag table

    const int tid = threadIdx.x;
    {
        // stage 40960 B: 256 threads x 10 x 16 B, coalesced, once per block
        const uint4* g = (const uint4*)frags;
        uint4* s = (uint4*)smem;
#pragma unroll
        for (int i = 0; i < 10; ++i) s[tid + i * 256] = g[tid + i * 256];
    }
    __syncthreads();

    const int lane = tid & 63;
    const int wid = tid >> 6;
    const int tile = blockIdx.x * 4 + wid;
    if (tile >= ntiles) return; // after the barrier: safe
    const int r = lane & 31, h = lane >> 5;
    const size_t row = (size_t)tile * 32 + r;

    const bf16x8* F = (const bf16x8*)smem; // F[phys*64 + lane], LDS-resident
    const float bc2 = norms[0], b02 = norms[1], b12 = norms[2];

    // ---- branches
    f32x16 d1[2], d2[2];
    float lam1, X2, lam2, Y2;
    branch_stage32(x1, row, h, lane, 0, F, d1, lam1, X2);
    branch_stage32(x2, row, h, lane, 4, F, d2, lam2, Y2);

    // ---- mobius_add(h1, h2), scales folded
    {
        float C = dotred32<2>(d1, d2);
        float xy = lam1 * lam2 * C;
        float a = 1.0f + 2.0f * xy + Y2;
        float b = 1.0f - X2;
        float den = fmaxf(fmaf(X2, Y2, 1.0f + 2.0f * xy), 1e-15f);
        float inv = 1.0f / den;
        float A = a * lam1, B = b * lam2;
#pragma unroll
        for (int t = 0; t < 2; ++t)
#pragma unroll
            for (int rr = 0; rr < 16; ++rr) d1[t][rr] = fmaf(A, d1[t][rr], B * d2[t][rr]);
        lam1 = inv;
        X2 = (a * a * X2 + 2.0f * a * b * xy + b * b * Y2) * (inv * inv);
    }
    // ---- + bc  (bias in D-register order)
    f32x16 bcv[2];
#pragma unroll
    for (int t = 0; t < 2; ++t) bcv[t] = loadb(bc, t * 32, h);
    mobius_bias_fold32<2>(d1, bcv, lam1, X2, bc2);
    logmap_fold(lam1, X2);

    // ---- layer 0 (K=64, kperm32'd weights; D regs feed B-frags in order)
    bf16x8 ah[4], al[4];
    split_d32(d1, ah, al);
    f32x16 d0[2];
    layer_mm32<2>(F, 8, lane, ah, al, d0);
    expmap_fold32<2>(d0, lam1, X2);
    f32x16 b0v[2];
#pragma unroll
    for (int t = 0; t < 2; ++t) b0v[t] = loadb(b0, t * 32, h);
    mobius_bias_fold32<2>(d0, b0v, lam1, X2, b02);
    logmap_fold(lam1, X2);

    // ---- layer 1 (N=32)
    split_d32(d0, ah, al);
    f32x16 dO[1];
    layer_mm32<1>(F, 16, lane, ah, al, dO);
    expmap_fold32<1>(dO, lam1, X2);

    // ---- final mobius bias, inv folded into the store scale
    f32x16 b1v = loadb(b1, 0, h);
    {
        float C = dotred32<1>(dO, &b1v);
        float xy = lam1 * C;
        float a = 1.0f + 2.0f * xy + b12;
        float b = 1.0f - X2;
        float den = fmaxf(fmaf(X2, b12, 1.0f + 2.0f * xy), 1e-15f);
        float inv = 1.0f / den;
        float F1 = inv * a * lam1, F2 = inv * b;
#pragma unroll
        for (int g = 0; g < 4; ++g) {
            f32x4 res;
#pragma unroll
            for (int k = 0; k < 4; ++k)
                res[k] = fmaf(F1, dO[0][g * 4 + k], F2 * b1v[g * 4 + k]);
            *(f32x4*)(out + row * 32 + g * 8 + h * 4) = res;
        }
    }
}

extern "C" void kernel_launch(void* const* d_in, const int* in_sizes, int n_in,
                              void* d_out, int out_size, void* d_ws, size_t ws_size,
                              hipStream_t stream) {
    const float* x1  = (const float*)d_in[0];
    const float* x2  = (const float*)d_in[1];
    const float* Wc1 = (const float*)d_in[2];
    const float* Wc2 = (const float*)d_in[3];
    const float* bc  = (const float*)d_in[4];
    const float* W0  = (const float*)d_in[5];
    const float* b0  = (const float*)d_in[6];
    const float* W1  = (const float*)d_in[7];
    const float* b1  = (const float*)d_in[8];
    float* out = (float*)d_out;

    unsigned short* frags = (unsigned short*)d_ws;            // 40 KB
    float* norms = (float*)((char*)d_ws + 40 * 512 * 2);      // 3 floats

    const int nrows  = in_sizes[0] / 32;
    const int ntiles = nrows / 32;       // 32-row tiles (N = 524288 divides)
    const int nblocks = (ntiles + 3) / 4;

    build_frags<<<81, 256, 0, stream>>>(Wc1, Wc2, W0, W1, bc, b0, b1, frags, norms);
    poincare_mfma6<<<nblocks, 256, 0, stream>>>(x1, x2, bc, b0, b1, frags, norms, out, ntiles);
}